// Round 15
// baseline (1395.566 us; speedup 1.0000x reference)
//
#include <hip/hip_runtime.h>
#include <math.h>

#define NF   1024
#define NB   2048
#define DIM  2048
#define NC   1000
#define IMG  150528   // 3*224*224, = 37632 float4
#define IMG4 37632
#define KSEL 8

typedef float f32x4 __attribute__((ext_vector_type(4)));

// ---------------- norms: 1/max(||row||,eps) for feats and bank ----------------
__global__ __launch_bounds__(256) void norms_kernel(
    const float* __restrict__ feats, const float* __restrict__ bank,
    float* __restrict__ invf, float* __restrict__ invb)
{
    int row = blockIdx.x;
    const float* src;
    float* dst;
    if (row < NF) { src = feats + (size_t)row * DIM; dst = invf + row; }
    else          { src = bank  + (size_t)(row - NF) * DIM; dst = invb + (row - NF); }

    float s = 0.f;
    for (int c = threadIdx.x; c < DIM / 4; c += 256) {
        float4 v = ((const float4*)src)[c];
        s += v.x * v.x + v.y * v.y + v.z * v.z + v.w * v.w;
    }
    __shared__ float red[4];
    for (int off = 32; off; off >>= 1) s += __shfl_down(s, off, 64);
    if ((threadIdx.x & 63) == 0) red[threadIdx.x >> 6] = s;
    __syncthreads();
    if (threadIdx.x == 0) {
        float t = red[0] + red[1] + red[2] + red[3];
        float n = fmaxf(sqrtf(t), 1e-12f);
        *dst = 1.0f / n;
    }
}

// ------ dist GEMM + fused per-block top-8 candidates -------------------------
// dist[i][j] = 1 - (A_i . B_j) * invf[i] * invb[j], never materialized to HBM.
// v3 structure: 512 threads (8 waves, 2/SIMD for latency hiding), 128x64
// tile. Wave w owns rows w*16..+15, lane = column. Per k: 4 WAVE-UNIFORM
// ds_read_b128 of A (LDS broadcast, 16B each - byte-cost ~free) + 1
// lane-strided ds_read_b32 of B (conflict-free) + 16 scalar fma.
// LDS traffic: 2.5 KB/k/CU vs 12 KB for the per-thread-8x4 layout -> FMA-
// issue-bound (~55us) instead of LDS-byte-bound (~120us).
// Register budget deliberately small: acc[16] + 4x float4 av (~70 VGPR).
// R13's failure was acc[32]+av[8] -> VGPR 256 -> scratch spill, NOT the
// broadcast mechanism. FMA chain per output = same ascending-k scalar
// sequence -> bit-identical dist values -> identical top-k selection.
// Epilogue: values -> LDS [128][65]; 1 thread/row insertion-scans ascending
// columns (strict '>' keeps lowest index on ties = jax.lax.top_k order),
// emitting 8 (val,idx) candidates per (row,colblock).
#define GBM 128
#define GBN 64
#define GBK 16
#define NCB (NB / GBN)   // 32 column blocks

__global__ __launch_bounds__(512) void dist_kernel(
    const float* __restrict__ A, const float* __restrict__ B,
    const float* __restrict__ invf, const float* __restrict__ invb,
    float* __restrict__ candv, int* __restrict__ candi)
{
    __shared__ float As[2][GBK][GBM];   // k-major, 16 KB
    __shared__ float Bs[2][GBK][GBN];   // k-major,  8 KB
    __shared__ float ep[GBM][GBN + 1];  // epilogue values, 33 KB

    const int tid  = threadIdx.x;
    const int brow = blockIdx.y * GBM;   // over NF
    const int bcol = blockIdx.x * GBN;   // over NB
    const int r0   = (tid >> 6) * 16;    // wave's first row (0,16,...,112)
    const int lane = tid & 63;           // column within tile

    const int lrowA = tid >> 2;          // 0..127 (A staging: 1 float4/thread)
    const int lkA   = (tid & 3) * 4;     // 0,4,8,12
    // B staging: threads 0..255 only (64 rows x 16 k = 256 float4)

    float acc[16] = {};

    // prologue: stage tile 0
    {
        float4 a0 = *(const float4*)(A + (size_t)(brow + lrowA) * DIM + lkA);
        As[0][lkA + 0][lrowA] = a0.x; As[0][lkA + 1][lrowA] = a0.y;
        As[0][lkA + 2][lrowA] = a0.z; As[0][lkA + 3][lrowA] = a0.w;
        if (tid < 256) {
            float4 b0 = *(const float4*)(B + (size_t)(bcol + lrowA) * DIM + lkA);
            Bs[0][lkA + 0][lrowA] = b0.x; Bs[0][lkA + 1][lrowA] = b0.y;
            Bs[0][lkA + 2][lrowA] = b0.z; Bs[0][lkA + 3][lrowA] = b0.w;
        }
    }
    __syncthreads();

    int cur = 0;
    for (int k0 = 0; k0 < DIM; k0 += GBK) {
        const bool has_next = (k0 + GBK) < DIM;
        float4 na, nb;
        if (has_next) {   // issue next tile's global loads (in flight under MACs)
            na = *(const float4*)(A + (size_t)(brow + lrowA) * DIM + k0 + GBK + lkA);
            if (tid < 256)
                nb = *(const float4*)(B + (size_t)(bcol + lrowA) * DIM + k0 + GBK + lkA);
        }

        #pragma unroll
        for (int k = 0; k < GBK; ++k) {
            float4 av0 = *(const float4*)&As[cur][k][r0 + 0];    // wave-uniform
            float4 av1 = *(const float4*)&As[cur][k][r0 + 4];    // (broadcast)
            float4 av2 = *(const float4*)&As[cur][k][r0 + 8];
            float4 av3 = *(const float4*)&As[cur][k][r0 + 12];
            float b = Bs[cur][k][lane];                          // lane-strided
            acc[0]  = fmaf(av0.x, b, acc[0]);
            acc[1]  = fmaf(av0.y, b, acc[1]);
            acc[2]  = fmaf(av0.z, b, acc[2]);
            acc[3]  = fmaf(av0.w, b, acc[3]);
            acc[4]  = fmaf(av1.x, b, acc[4]);
            acc[5]  = fmaf(av1.y, b, acc[5]);
            acc[6]  = fmaf(av1.z, b, acc[6]);
            acc[7]  = fmaf(av1.w, b, acc[7]);
            acc[8]  = fmaf(av2.x, b, acc[8]);
            acc[9]  = fmaf(av2.y, b, acc[9]);
            acc[10] = fmaf(av2.z, b, acc[10]);
            acc[11] = fmaf(av2.w, b, acc[11]);
            acc[12] = fmaf(av3.x, b, acc[12]);
            acc[13] = fmaf(av3.y, b, acc[13]);
            acc[14] = fmaf(av3.z, b, acc[14]);
            acc[15] = fmaf(av3.w, b, acc[15]);
        }

        if (has_next) {
            const int nxt = cur ^ 1;
            As[nxt][lkA + 0][lrowA] = na.x; As[nxt][lkA + 1][lrowA] = na.y;
            As[nxt][lkA + 2][lrowA] = na.z; As[nxt][lkA + 3][lrowA] = na.w;
            if (tid < 256) {
                Bs[nxt][lkA + 0][lrowA] = nb.x; Bs[nxt][lkA + 1][lrowA] = nb.y;
                Bs[nxt][lkA + 2][lrowA] = nb.z; Bs[nxt][lkA + 3][lrowA] = nb.w;
            }
        }
        __syncthreads();
        cur ^= 1;
    }

    // epilogue: dist values -> LDS (one row per instruction across 64 lanes:
    // consecutive addresses, conflict-free)
    {
        const float fb = invb[bcol + lane];
        #pragma unroll
        for (int r = 0; r < 16; ++r) {
            const float fi = invf[brow + r0 + r];   // wave-uniform -> s_load
            ep[r0 + r][lane] = 1.0f - acc[r] * fi * fb;
        }
    }
    __syncthreads();

    // per-row top-8 of 64 (ascending col scan; strict '>' -> lowest idx wins ties)
    if (tid < GBM) {
        float lv[KSEL];
        int   li[KSEL];
        #pragma unroll
        for (int s = 0; s < KSEL; ++s) { lv[s] = -1e30f; li[s] = NB; }
        for (int c = 0; c < GBN; ++c) {
            float v = ep[tid][c];
            if (v > lv[KSEL - 1]) {
                lv[KSEL - 1] = v; li[KSEL - 1] = bcol + c;
                #pragma unroll
                for (int p = KSEL - 1; p > 0; --p) {
                    if (lv[p] > lv[p - 1]) {
                        float tv = lv[p]; lv[p] = lv[p - 1]; lv[p - 1] = tv;
                        int   ti = li[p]; li[p] = li[p - 1]; li[p - 1] = ti;
                    }
                }
            }
        }
        size_t base = ((size_t)(brow + tid) * NCB + blockIdx.x) * KSEL;
        #pragma unroll
        for (int s = 0; s < KSEL; ++s) {
            candv[base + s] = lv[s];
            candi[base + s] = li[s];
        }
    }
}

// ------- final top-8 over 256 candidates/row (val desc, idx asc) -------------
__global__ __launch_bounds__(256) void final_topk_kernel(
    const float* __restrict__ candv, const int* __restrict__ candi,
    int* __restrict__ idxs)
{
    const int row = blockIdx.x;
    const int t = threadIdx.x;
    __shared__ float cv[256];
    __shared__ int   ci[256];
    __shared__ float rv[256];
    __shared__ int   ri[256];
    cv[t] = candv[(size_t)row * 256 + t];
    ci[t] = candi[(size_t)row * 256 + t];
    __syncthreads();

    for (int sel = 0; sel < KSEL; ++sel) {
        rv[t] = cv[t]; ri[t] = ci[t];
        __syncthreads();
        for (int s = 128; s; s >>= 1) {
            if (t < s) {
                float ov = rv[t + s]; int oi = ri[t + s];
                if (ov > rv[t] || (ov == rv[t] && oi < ri[t])) {
                    rv[t] = ov; ri[t] = oi;
                }
            }
            __syncthreads();
        }
        if (t == 0) idxs[row * KSEL + sel] = ri[0];
        // invalidate the winner (unique: each idx occurs in exactly one block)
        if (cv[t] == rv[0] && ci[t] == ri[0]) cv[t] = -1e30f;
        __syncthreads();
    }
}

// -------- fused gather: probs+labels | grads | images, one kernel ------------
// images: XCD-L2-targeted column tiling (2 KB slice/image -> 4 MB tile
// footprint on one XCD's L2; all blocks of tile t satisfy blockIdx%8 == t%8).
// Best-measured geometry (R10/R11/R14, ~647us total). Two thread-halves of
// 128 lanes, RPB=4 rows each; 32 independent pinned global_load_dwordx4 per
// thread; non-temporal output stores.
#define ITILES 294                    // 294 tiles * 128 float4 = 37632 = IMG4
#define RPB    4                      // rows per thread-half
#define NIMGB  (ITILES * (NF / 8))   // 294 * 128 = 37632 images blocks

__global__ __launch_bounds__(256) void gather_kernel(
    const float* __restrict__ bank_probs, const float* __restrict__ bank_feats,
    const float* __restrict__ image_bank, const int* __restrict__ idxs,
    float* __restrict__ out_labels, float* __restrict__ out_probs,
    float* __restrict__ out_grads,  float* __restrict__ out_images)
{
    const int gid = blockIdx.x;
    const int t = threadIdx.x;
    __shared__ int   id[KSEL];
    __shared__ float rv[256];
    __shared__ int   ri[256];

    if (gid < NF) {
        // ---- probs + labels, row = gid ----
        const int row = gid;
        if (t < KSEL) id[t] = idxs[row * KSEL + t];
        __syncthreads();
        float bv = -1e30f; int bc = NC;
        for (int c = t; c < NC; c += 256) {
            float s = 0.f;
            #pragma unroll
            for (int k = 0; k < KSEL; ++k) s += bank_probs[(size_t)id[k] * NC + c];
            s *= (1.0f / KSEL);
            out_probs[(size_t)row * NC + c] = s;
            if (s > bv) { bv = s; bc = c; }
        }
        rv[t] = bv; ri[t] = bc;
        __syncthreads();
        for (int s = 128; s; s >>= 1) {
            if (t < s) {
                float ov = rv[t + s]; int oi = ri[t + s];
                if (ov > rv[t] || (ov == rv[t] && oi < ri[t])) {
                    rv[t] = ov; ri[t] = oi;
                }
            }
            __syncthreads();
        }
        if (t == 0) out_labels[row] = (float)ri[0];
    } else if (gid < 2 * NF) {
        // ---- grads, row = gid - NF ----
        const int row = gid - NF;
        if (t < KSEL) id[t] = idxs[row * KSEL + t];
        __syncthreads();
        for (int c = t; c < DIM / 4; c += 256) {
            f32x4 acc = {0.f, 0.f, 0.f, 0.f};
            #pragma unroll
            for (int k = 0; k < KSEL; ++k)
                acc += ((const f32x4*)(bank_feats + (size_t)id[k] * DIM))[c];
            ((f32x4*)(out_grads + (size_t)row * DIM))[c] = acc * 0.125f;
        }
    } else {
        // ---- images ----
        const int b = gid - 2 * NF;          // 0..37631, b%8 == tile%8
        int tile, rowblk;
        if (b < 36864) {                     // 36 full groups of 8 tiles
            const int group  = b >> 10;      // /1024
            const int within = b & 1023;
            rowblk = within >> 3;            // 0..127
            tile   = group * 8 + (within & 7);
        } else {                             // tail: tiles 288..293
            const int bb = b - 36864;        // 0..767
            tile   = 288 + bb % 6;
            rowblk = bb / 6;                 // 0..127
        }
        const int half = t >> 7;             // 0 or 1
        const int lane = t & 127;
        const int row0 = rowblk * 8 + half * RPB;
        const int base4 = tile * 128 + lane;

        const int* __restrict__ ip = idxs + row0 * KSEL;
        const f32x4* __restrict__ bank4 = (const f32x4*)image_bank;

        f32x4 v[RPB][KSEL];
        #pragma unroll
        for (int r = 0; r < RPB; ++r)
            #pragma unroll
            for (int k = 0; k < KSEL; ++k)
                v[r][k] = bank4[(size_t)ip[r * KSEL + k] * IMG4 + base4];
        __builtin_amdgcn_sched_barrier(0);   // pin: all 32 loads issued first

        #pragma unroll
        for (int r = 0; r < RPB; ++r) {
            f32x4 s01 = v[r][0] + v[r][1];
            f32x4 s23 = v[r][2] + v[r][3];
            f32x4 s45 = v[r][4] + v[r][5];
            f32x4 s67 = v[r][6] + v[r][7];
            f32x4 o = ((s01 + s23) + (s45 + s67)) * 0.125f;
            f32x4* outp = (f32x4*)(out_images + (size_t)(row0 + r) * IMG) + base4;
            __builtin_nontemporal_store(o, outp);
        }
    }
}

extern "C" void kernel_launch(void* const* d_in, const int* in_sizes, int n_in,
                              void* d_out, int out_size, void* d_ws, size_t ws_size,
                              hipStream_t stream)
{
    const float* feats      = (const float*)d_in[0];
    const float* bank_feats = (const float*)d_in[1];
    const float* bank_probs = (const float*)d_in[2];
    const float* image_bank = (const float*)d_in[3];

    float* out = (float*)d_out;
    // output layout: labels[1024] | probs[1024*1000] | images[1024*150528] | grads[1024*2048]
    float* out_labels = out;
    float* out_probs  = out + NF;
    float* out_images = out + NF + (size_t)NF * NC;
    float* out_grads  = out + NF + (size_t)NF * NC + (size_t)NF * IMG;

    // d_ws: invf[NF] | invb[NB] | idxs[NF*8] | candv[NF*256] | candi[NF*256]  (~2.1 MB)
    float* invf  = (float*)d_ws;
    float* invb  = invf + NF;
    int*   idxs  = (int*)(invb + NB);
    float* candv = (float*)(idxs + NF * KSEL);
    int*   candi = (int*)(candv + (size_t)NF * NCB * KSEL);

    norms_kernel<<<NF + NB, 256, 0, stream>>>(feats, bank_feats, invf, invb);

    dim3 ggrid(NCB, NF / GBM);   // (32, 8) = 256 workgroups, 512 threads each
    dist_kernel<<<ggrid, 512, 0, stream>>>(feats, bank_feats, invf, invb, candv, candi);

    final_topk_kernel<<<NF, 256, 0, stream>>>(candv, candi, idxs);

    gather_kernel<<<2 * NF + NIMGB, 256, 0, stream>>>(
        bank_probs, bank_feats, image_bank, idxs,
        out_labels, out_probs, out_grads, out_images);
}

// Round 16
// 646.452 us; speedup vs baseline: 2.1588x; 2.1588x over previous
//
#include <hip/hip_runtime.h>
#include <math.h>

#define NF   1024
#define NB   2048
#define DIM  2048
#define NC   1000
#define IMG  150528   // 3*224*224, = 37632 float4
#define IMG4 37632
#define KSEL 8

typedef float f32x4 __attribute__((ext_vector_type(4)));
typedef float f32x2 __attribute__((ext_vector_type(2)));

// ---------------- norms: 1/max(||row||,eps) for feats and bank ----------------
__global__ __launch_bounds__(256) void norms_kernel(
    const float* __restrict__ feats, const float* __restrict__ bank,
    float* __restrict__ invf, float* __restrict__ invb)
{
    int row = blockIdx.x;
    const float* src;
    float* dst;
    if (row < NF) { src = feats + (size_t)row * DIM; dst = invf + row; }
    else          { src = bank  + (size_t)(row - NF) * DIM; dst = invb + (row - NF); }

    float s = 0.f;
    for (int c = threadIdx.x; c < DIM / 4; c += 256) {
        float4 v = ((const float4*)src)[c];
        s += v.x * v.x + v.y * v.y + v.z * v.z + v.w * v.w;
    }
    __shared__ float red[4];
    for (int off = 32; off; off >>= 1) s += __shfl_down(s, off, 64);
    if ((threadIdx.x & 63) == 0) red[threadIdx.x >> 6] = s;
    __syncthreads();
    if (threadIdx.x == 0) {
        float t = red[0] + red[1] + red[2] + red[3];
        float n = fmaxf(sqrtf(t), 1e-12f);
        *dst = 1.0f / n;
    }
}

// ------ dist GEMM + fused per-block top-8 candidates -------------------------
// dist[i][j] = 1 - (A_i . B_j) * invf[i] * invb[j], never materialized to HBM.
// PROVEN structure (R7-R11/R14, ~150us): per-thread 8x4 tile, f32x2 packed
// FMA, double-buffered LDS, one barrier per K-step.
// REFUTED alternatives (do not revisit): LDS-broadcast wave-uniform
// ds_read_b128 A-fragments (R13: VGPR 256 spill; R15: VGPR 128 + 3.3 GB
// scratch AND 9.4M bank conflicts -> wave-uniform b128 reads are NOT free
// broadcasts on gfx950, only b32 is).
// Epilogue: values -> LDS [128][65]; 1 thread/row insertion-scans ascending
// columns (strict '>' keeps lowest index on ties = jax.lax.top_k order),
// emitting 8 (val,idx) candidates per (row,colblock).
#define GBM 128
#define GBN 64
#define GBK 16
#define NCB (NB / GBN)   // 32 column blocks

__global__ __launch_bounds__(256) void dist_kernel(
    const float* __restrict__ A, const float* __restrict__ B,
    const float* __restrict__ invf, const float* __restrict__ invb,
    float* __restrict__ candv, int* __restrict__ candi)
{
    __shared__ float As[2][GBK][GBM];   // k-major
    __shared__ float Bs[2][GBK][GBN];
    __shared__ float ep[GBM][GBN + 1];  // epilogue values, +1 pad

    const int tid  = threadIdx.x;
    const int brow = blockIdx.y * GBM;   // over NF
    const int bcol = blockIdx.x * GBN;   // over NB
    const int ty   = tid >> 4;           // 0..15 -> rows ty*8..+7
    const int tx   = tid & 15;           // 0..15 -> cols tx*4..+3

    const int lrow = tid >> 2;           // 0..63
    const int lk   = (tid & 3) * 4;      // 0,4,8,12

    f32x2 acc01[8] = {};
    f32x2 acc23[8] = {};

    // prologue: stage tile 0
    {
        float4 a0 = *(const float4*)(A + (size_t)(brow + lrow)      * DIM + lk);
        float4 a1 = *(const float4*)(A + (size_t)(brow + lrow + 64) * DIM + lk);
        float4 b0 = *(const float4*)(B + (size_t)(bcol + lrow)      * DIM + lk);
        As[0][lk + 0][lrow] = a0.x; As[0][lk + 1][lrow] = a0.y;
        As[0][lk + 2][lrow] = a0.z; As[0][lk + 3][lrow] = a0.w;
        As[0][lk + 0][lrow + 64] = a1.x; As[0][lk + 1][lrow + 64] = a1.y;
        As[0][lk + 2][lrow + 64] = a1.z; As[0][lk + 3][lrow + 64] = a1.w;
        Bs[0][lk + 0][lrow] = b0.x; Bs[0][lk + 1][lrow] = b0.y;
        Bs[0][lk + 2][lrow] = b0.z; Bs[0][lk + 3][lrow] = b0.w;
    }
    __syncthreads();

    int cur = 0;
    for (int k0 = 0; k0 < DIM; k0 += GBK) {
        const bool has_next = (k0 + GBK) < DIM;
        float4 na0, na1, nb0;
        if (has_next) {   // issue next tile's global loads (in flight under MACs)
            na0 = *(const float4*)(A + (size_t)(brow + lrow)      * DIM + k0 + GBK + lk);
            na1 = *(const float4*)(A + (size_t)(brow + lrow + 64) * DIM + k0 + GBK + lk);
            nb0 = *(const float4*)(B + (size_t)(bcol + lrow)      * DIM + k0 + GBK + lk);
        }

        #pragma unroll
        for (int k = 0; k < GBK; ++k) {
            float4 av0 = *(const float4*)&As[cur][k][ty * 8];
            float4 av1 = *(const float4*)&As[cur][k][ty * 8 + 4];
            float4 bv  = *(const float4*)&Bs[cur][k][tx * 4];
            f32x2 b01 = {bv.x, bv.y};
            f32x2 b23 = {bv.z, bv.w};
            float a[8] = {av0.x, av0.y, av0.z, av0.w, av1.x, av1.y, av1.z, av1.w};
            #pragma unroll
            for (int i = 0; i < 8; ++i) {
                f32x2 ai = {a[i], a[i]};
                acc01[i] = __builtin_elementwise_fma(ai, b01, acc01[i]);
                acc23[i] = __builtin_elementwise_fma(ai, b23, acc23[i]);
            }
        }

        if (has_next) {
            const int nxt = cur ^ 1;
            As[nxt][lk + 0][lrow] = na0.x; As[nxt][lk + 1][lrow] = na0.y;
            As[nxt][lk + 2][lrow] = na0.z; As[nxt][lk + 3][lrow] = na0.w;
            As[nxt][lk + 0][lrow + 64] = na1.x; As[nxt][lk + 1][lrow + 64] = na1.y;
            As[nxt][lk + 2][lrow + 64] = na1.z; As[nxt][lk + 3][lrow + 64] = na1.w;
            Bs[nxt][lk + 0][lrow] = nb0.x; Bs[nxt][lk + 1][lrow] = nb0.y;
            Bs[nxt][lk + 2][lrow] = nb0.z; Bs[nxt][lk + 3][lrow] = nb0.w;
        }
        __syncthreads();
        cur ^= 1;
    }

    // epilogue: dist values -> LDS
    float fi[8], fb[4];
    #pragma unroll
    for (int i = 0; i < 8; ++i) fi[i] = invf[brow + ty * 8 + i];
    #pragma unroll
    for (int j = 0; j < 4; ++j) fb[j] = invb[bcol + tx * 4 + j];
    #pragma unroll
    for (int i = 0; i < 8; ++i) {
        ep[ty * 8 + i][tx * 4 + 0] = 1.0f - acc01[i].x * fi[i] * fb[0];
        ep[ty * 8 + i][tx * 4 + 1] = 1.0f - acc01[i].y * fi[i] * fb[1];
        ep[ty * 8 + i][tx * 4 + 2] = 1.0f - acc23[i].x * fi[i] * fb[2];
        ep[ty * 8 + i][tx * 4 + 3] = 1.0f - acc23[i].y * fi[i] * fb[3];
    }
    __syncthreads();

    // per-row top-8 of 64 (ascending col scan; strict '>' -> lowest idx wins ties)
    if (tid < GBM) {
        float lv[KSEL];
        int   li[KSEL];
        #pragma unroll
        for (int s = 0; s < KSEL; ++s) { lv[s] = -1e30f; li[s] = NB; }
        for (int c = 0; c < GBN; ++c) {
            float v = ep[tid][c];
            if (v > lv[KSEL - 1]) {
                lv[KSEL - 1] = v; li[KSEL - 1] = bcol + c;
                #pragma unroll
                for (int p = KSEL - 1; p > 0; --p) {
                    if (lv[p] > lv[p - 1]) {
                        float tv = lv[p]; lv[p] = lv[p - 1]; lv[p - 1] = tv;
                        int   ti = li[p]; li[p] = li[p - 1]; li[p - 1] = ti;
                    }
                }
            }
        }
        size_t base = ((size_t)(brow + tid) * NCB + blockIdx.x) * KSEL;
        #pragma unroll
        for (int s = 0; s < KSEL; ++s) {
            candv[base + s] = lv[s];
            candi[base + s] = li[s];
        }
    }
}

// ------- final top-8 over 256 candidates/row (val desc, idx asc) -------------
__global__ __launch_bounds__(256) void final_topk_kernel(
    const float* __restrict__ candv, const int* __restrict__ candi,
    int* __restrict__ idxs)
{
    const int row = blockIdx.x;
    const int t = threadIdx.x;
    __shared__ float cv[256];
    __shared__ int   ci[256];
    __shared__ float rv[256];
    __shared__ int   ri[256];
    cv[t] = candv[(size_t)row * 256 + t];
    ci[t] = candi[(size_t)row * 256 + t];
    __syncthreads();

    for (int sel = 0; sel < KSEL; ++sel) {
        rv[t] = cv[t]; ri[t] = ci[t];
        __syncthreads();
        for (int s = 128; s; s >>= 1) {
            if (t < s) {
                float ov = rv[t + s]; int oi = ri[t + s];
                if (ov > rv[t] || (ov == rv[t] && oi < ri[t])) {
                    rv[t] = ov; ri[t] = oi;
                }
            }
            __syncthreads();
        }
        if (t == 0) idxs[row * KSEL + sel] = ri[0];
        // invalidate the winner (unique: each idx occurs in exactly one block)
        if (cv[t] == rv[0] && ci[t] == ri[0]) cv[t] = -1e30f;
        __syncthreads();
    }
}

// -------- fused gather: probs+labels | grads | images, one kernel ------------
// images: XCD-L2-targeted column tiling (2 KB slice/image -> 4 MB tile
// footprint on one XCD's L2; all blocks of tile t satisfy blockIdx%8 == t%8).
// Best-measured geometry (R10/R11/R14, 646.9-647.7us total). Two thread-
// halves of 128 lanes, RPB=4 rows each; 32 independent pinned
// global_load_dwordx4 per thread; non-temporal output stores.
#define ITILES 294                    // 294 tiles * 128 float4 = 37632 = IMG4
#define RPB    4                      // rows per thread-half
#define NIMGB  (ITILES * (NF / 8))   // 294 * 128 = 37632 images blocks

__global__ __launch_bounds__(256) void gather_kernel(
    const float* __restrict__ bank_probs, const float* __restrict__ bank_feats,
    const float* __restrict__ image_bank, const int* __restrict__ idxs,
    float* __restrict__ out_labels, float* __restrict__ out_probs,
    float* __restrict__ out_grads,  float* __restrict__ out_images)
{
    const int gid = blockIdx.x;
    const int t = threadIdx.x;
    __shared__ int   id[KSEL];
    __shared__ float rv[256];
    __shared__ int   ri[256];

    if (gid < NF) {
        // ---- probs + labels, row = gid ----
        const int row = gid;
        if (t < KSEL) id[t] = idxs[row * KSEL + t];
        __syncthreads();
        float bv = -1e30f; int bc = NC;
        for (int c = t; c < NC; c += 256) {
            float s = 0.f;
            #pragma unroll
            for (int k = 0; k < KSEL; ++k) s += bank_probs[(size_t)id[k] * NC + c];
            s *= (1.0f / KSEL);
            out_probs[(size_t)row * NC + c] = s;
            if (s > bv) { bv = s; bc = c; }
        }
        rv[t] = bv; ri[t] = bc;
        __syncthreads();
        for (int s = 128; s; s >>= 1) {
            if (t < s) {
                float ov = rv[t + s]; int oi = ri[t + s];
                if (ov > rv[t] || (ov == rv[t] && oi < ri[t])) {
                    rv[t] = ov; ri[t] = oi;
                }
            }
            __syncthreads();
        }
        if (t == 0) out_labels[row] = (float)ri[0];
    } else if (gid < 2 * NF) {
        // ---- grads, row = gid - NF ----
        const int row = gid - NF;
        if (t < KSEL) id[t] = idxs[row * KSEL + t];
        __syncthreads();
        for (int c = t; c < DIM / 4; c += 256) {
            f32x4 acc = {0.f, 0.f, 0.f, 0.f};
            #pragma unroll
            for (int k = 0; k < KSEL; ++k)
                acc += ((const f32x4*)(bank_feats + (size_t)id[k] * DIM))[c];
            ((f32x4*)(out_grads + (size_t)row * DIM))[c] = acc * 0.125f;
        }
    } else {
        // ---- images ----
        const int b = gid - 2 * NF;          // 0..37631, b%8 == tile%8
        int tile, rowblk;
        if (b < 36864) {                     // 36 full groups of 8 tiles
            const int group  = b >> 10;      // /1024
            const int within = b & 1023;
            rowblk = within >> 3;            // 0..127
            tile   = group * 8 + (within & 7);
        } else {                             // tail: tiles 288..293
            const int bb = b - 36864;        // 0..767
            tile   = 288 + bb % 6;
            rowblk = bb / 6;                 // 0..127
        }
        const int half = t >> 7;             // 0 or 1
        const int lane = t & 127;
        const int row0 = rowblk * 8 + half * RPB;
        const int base4 = tile * 128 + lane;

        const int* __restrict__ ip = idxs + row0 * KSEL;
        const f32x4* __restrict__ bank4 = (const f32x4*)image_bank;

        f32x4 v[RPB][KSEL];
        #pragma unroll
        for (int r = 0; r < RPB; ++r)
            #pragma unroll
            for (int k = 0; k < KSEL; ++k)
                v[r][k] = bank4[(size_t)ip[r * KSEL + k] * IMG4 + base4];
        __builtin_amdgcn_sched_barrier(0);   // pin: all 32 loads issued first

        #pragma unroll
        for (int r = 0; r < RPB; ++r) {
            f32x4 s01 = v[r][0] + v[r][1];
            f32x4 s23 = v[r][2] + v[r][3];
            f32x4 s45 = v[r][4] + v[r][5];
            f32x4 s67 = v[r][6] + v[r][7];
            f32x4 o = ((s01 + s23) + (s45 + s67)) * 0.125f;
            f32x4* outp = (f32x4*)(out_images + (size_t)(row0 + r) * IMG) + base4;
            __builtin_nontemporal_store(o, outp);
        }
    }
}

extern "C" void kernel_launch(void* const* d_in, const int* in_sizes, int n_in,
                              void* d_out, int out_size, void* d_ws, size_t ws_size,
                              hipStream_t stream)
{
    const float* feats      = (const float*)d_in[0];
    const float* bank_feats = (const float*)d_in[1];
    const float* bank_probs = (const float*)d_in[2];
    const float* image_bank = (const float*)d_in[3];

    float* out = (float*)d_out;
    // output layout: labels[1024] | probs[1024*1000] | images[1024*150528] | grads[1024*2048]
    float* out_labels = out;
    float* out_probs  = out + NF;
    float* out_images = out + NF + (size_t)NF * NC;
    float* out_grads  = out + NF + (size_t)NF * NC + (size_t)NF * IMG;

    // d_ws: invf[NF] | invb[NB] | idxs[NF*8] | candv[NF*256] | candi[NF*256]  (~2.1 MB)
    float* invf  = (float*)d_ws;
    float* invb  = invf + NF;
    int*   idxs  = (int*)(invb + NB);
    float* candv = (float*)(idxs + NF * KSEL);
    int*   candi = (int*)(candv + (size_t)NF * NCB * KSEL);

    norms_kernel<<<NF + NB, 256, 0, stream>>>(feats, bank_feats, invf, invb);

    dim3 ggrid(NCB, NF / GBM);   // (32, 8) = 256 workgroups
    dist_kernel<<<ggrid, 256, 0, stream>>>(feats, bank_feats, invf, invb, candv, candi);

    final_topk_kernel<<<NF, 256, 0, stream>>>(candv, candi, idxs);

    gather_kernel<<<2 * NF + NIMGB, 256, 0, stream>>>(
        bank_probs, bank_feats, image_bank, idxs,
        out_labels, out_probs, out_grads, out_images);
}